// Round 3
// baseline (1306.079 us; speedup 1.0000x reference)
//
#include <hip/hip_runtime.h>
#include <hip/hip_bf16.h>

// ---- static problem geometry (from reference: IMAGE_SIZES // 14) ----
// hp x wp per image: (110,110)(80,110)(110,64)(56,90)(108,108)(110,80)(64,64)(90,110)
// token counts: 12100 8800 7040 5040 11664 8800 4096 9900  -> 67440
// merged (n/4): 3025 2200 1760 1260 2916 2200 1024 2475    -> 16860
#define MTOK  16860
#define MPAD  16896   // 132 * 128
#define NOUT  1024
#define KDIM  4096

__device__ __constant__ int c_mend[8] = {3025,5225,6985,8245,11161,13361,14385,16860};
__device__ __constant__ int c_moff[8] = {0,3025,5225,6985,8245,11161,13361,14385};
__device__ __constant__ int c_foff[8] = {0,12100,20900,27940,32980,44644,53444,57540};
__device__ __constant__ int c_wp[8]   = {110,110,64,90,108,80,64,110};

typedef __attribute__((ext_vector_type(8))) short          bf16x8;  // 8 bf16 = 4 VGPRs
typedef __attribute__((ext_vector_type(8))) unsigned short u16x8;
typedef __attribute__((ext_vector_type(4))) float          f32x4;

__device__ __forceinline__ unsigned short f2bf(float f) {
    unsigned int u = __float_as_uint(f);
    u += 0x7FFFu + ((u >> 16) & 1u);   // round-to-nearest-even
    return (unsigned short)(u >> 16);
}

__device__ __forceinline__ void async_copy16(const void* g, void* l) {
    __builtin_amdgcn_global_load_lds(
        (const __attribute__((address_space(1))) void*)g,
        (__attribute__((address_space(3))) void*)l, 16, 0, 0);
}

// ---- kernel 1: weight fp32 -> bf16 (already [N][K] row-major = B^T) ----
__global__ __launch_bounds__(256) void cast_w(const float* __restrict__ W,
                                              unsigned short* __restrict__ Wb) {
    size_t g = (size_t)(blockIdx.x * 256 + threadIdx.x) * 4;
    float4 v = *(const float4*)(W + g);
    *(ushort4*)(Wb + g) = make_ushort4(f2bf(v.x), f2bf(v.y), f2bf(v.z), f2bf(v.w));
}

// ---- kernel 2: fused merge + GEMM.  C[M,N] = unfold(feats)[M,K] * Wb[N,K]^T ----
// A is staged straight from fp32 feats: thread t owns A-tile row r = t>>1,
// half = t&1 covers channels [half*16, half*16+16) of the BK=32 slice.
// Channel c = d*4 + ki*2 + kj  ->  d = d0 + half*4 + dd, source row (ki,kj).
// A-regs for iter k+1 are prefetched during the MFMA phase (latency overlap).
#define BM 128
#define BN 128
#define BK 32
__global__ __launch_bounds__(256) void gemm_fused(const float* __restrict__ feats,
                                                  const unsigned short* __restrict__ B,
                                                  float* __restrict__ C) {
    __shared__ unsigned short lA[BM * BK];   // 8 KiB
    __shared__ unsigned short lB[BN * BK];   // 8 KiB

    const int bn = blockIdx.x, bm = blockIdx.y;
    const int tid  = threadIdx.x;
    const int wave = tid >> 6, lane = tid & 63;
    const int wm = (wave >> 1) * 64, wn = (wave & 1) * 64;

    const int lrow = lane >> 2;          // 0..15
    const int lcol = (lane & 3) * 8;     // 0,8,16,24 (bf16 elems)

    // ---- per-thread A-row geometry (hoisted out of K-loop) ----
    const int r    = tid >> 1;           // A-tile row 0..127
    const int half = tid & 1;            // channel half: d-offset half*4
    const int trow = bm * BM + r;
    const bool valid = (trow < MTOK);
    {
    }
    int tt = valid ? trow : 0;
    int im = 0;
    while (tt >= c_mend[im]) im++;
    int rr  = tt - c_moff[im];
    int wp  = c_wp[im];
    int wp2 = wp >> 1;
    int i = rr / wp2, j = rr - i * wp2;
    const float* p00 = feats + (size_t)(c_foff[im] + (2*i)*wp + 2*j) * 1024 + half * 4;
    const float* p01 = p00 + 1024;
    const float* p10 = p00 + (size_t)wp * 1024;
    const float* p11 = p10 + 1024;

    const unsigned short* Bbase = B + (size_t)bn * BN * KDIM;

    f32x4 acc[4][4];
#pragma unroll
    for (int a = 0; a < 4; ++a)
#pragma unroll
        for (int b = 0; b < 4; ++b) acc[a][b] = (f32x4){0.f, 0.f, 0.f, 0.f};

    const int mrow = lane & 15;
    const int kq   = (lane >> 4) * 8;    // 0,8,16,24

    // prefetch iteration 0 (d0 = 0)
    float4 va = *(const float4*)(p00);
    float4 vb = *(const float4*)(p01);
    float4 vc = *(const float4*)(p10);
    float4 vd = *(const float4*)(p11);

    for (int k0 = 0; k0 < KDIM; k0 += BK) {
        // ---- stage A from regs (bf16, unfold-interleaved) ----
        u16x8 lo, hi;
        lo[0]=f2bf(va.x); lo[1]=f2bf(vb.x); lo[2]=f2bf(vc.x); lo[3]=f2bf(vd.x);
        lo[4]=f2bf(va.y); lo[5]=f2bf(vb.y); lo[6]=f2bf(vc.y); lo[7]=f2bf(vd.y);
        hi[0]=f2bf(va.z); hi[1]=f2bf(vb.z); hi[2]=f2bf(vc.z); hi[3]=f2bf(vd.z);
        hi[4]=f2bf(va.w); hi[5]=f2bf(vb.w); hi[6]=f2bf(vc.w); hi[7]=f2bf(vd.w);
        if (!valid) { lo = (u16x8)0; hi = (u16x8)0; }
        unsigned short* dst = &lA[r * BK + half * 16];
        *(u16x8*)(dst)     = lo;
        *(u16x8*)(dst + 8) = hi;

        // ---- stage B via async global->LDS ----
#pragma unroll
        for (int r2 = 0; r2 < 2; ++r2) {
            int chunk = wave * 2 + r2;           // 0..7 (1 KiB LDS chunks)
            int row   = chunk * 16 + lrow;       // 0..127
            async_copy16(Bbase + (size_t)row * KDIM + k0 + lcol, &lB[chunk * 512 + lane * 8]);
        }
        __syncthreads();   // drains ds_write + B async; LDS ready

        // ---- prefetch next iter's A (latency overlaps MFMA below) ----
        int doffn = ((k0 + BK) & (KDIM - 1)) >> 2;  // float offset; wraps on last iter
        float4 na = *(const float4*)(p00 + doffn);
        float4 nb = *(const float4*)(p01 + doffn);
        float4 nc = *(const float4*)(p10 + doffn);
        float4 nd = *(const float4*)(p11 + doffn);

        // ---- MFMA ----
        bf16x8 af[4], bfr[4];
#pragma unroll
        for (int a = 0; a < 4; ++a) {
            af[a]  = *(const bf16x8*)&lA[(wm + a * 16 + mrow) * BK + kq];
            bfr[a] = *(const bf16x8*)&lB[(wn + a * 16 + mrow) * BK + kq];
        }
#pragma unroll
        for (int a = 0; a < 4; ++a)
#pragma unroll
            for (int b = 0; b < 4; ++b)
                acc[a][b] = __builtin_amdgcn_mfma_f32_16x16x32_bf16(af[a], bfr[b], acc[a][b], 0, 0, 0);
        __syncthreads();   // protect LDS before next stage (also drains prefetch)

        va = na; vb = nb; vc = nc; vd = nd;
    }

    // epilogue: C/D layout col=lane&15, row=(lane>>4)*4+reg
    const int col   = lane & 15;
    const int rquad = (lane >> 4) * 4;
#pragma unroll
    for (int a = 0; a < 4; ++a) {
        int gm0 = bm * BM + wm + a * 16 + rquad;
#pragma unroll
        for (int b = 0; b < 4; ++b) {
            int gn = bn * BN + wn + b * 16 + col;
#pragma unroll
            for (int rg = 0; rg < 4; ++rg) {
                int gm = gm0 + rg;
                if (gm < MTOK) C[(size_t)gm * NOUT + gn] = acc[a][b][rg];
            }
        }
    }
}

// ---- fallback (ws too small): exact fp32, slow but correct ----
__global__ __launch_bounds__(256) void naive_fb(const float* __restrict__ feats,
                                                const float* __restrict__ W,
                                                float* __restrict__ out) {
    int t = blockIdx.x;
    int o = blockIdx.y * 256 + threadIdx.x;
    int im = 0;
    while (t >= c_mend[im]) im++;
    int r = t - c_moff[im];
    int wp = c_wp[im], wp2 = wp >> 1;
    int i = r / wp2, j = r - i * wp2;
    const float* f00 = feats + (size_t)(c_foff[im] + (2*i)*wp + 2*j) * 1024;
    const float* f10 = f00 + (size_t)wp * 1024;
    const float* w = W + (size_t)o * 4096;
    float s = 0.f;
    for (int d = 0; d < 1024; ++d)
        s += f00[d] * w[d*4] + f00[d+1024] * w[d*4+1] + f10[d] * w[d*4+2] + f10[d+1024] * w[d*4+3];
    out[(size_t)t * 1024 + o] = s;
}

extern "C" void kernel_launch(void* const* d_in, const int* in_sizes, int n_in,
                              void* d_out, int out_size, void* d_ws, size_t ws_size,
                              hipStream_t stream) {
    const float* feats = (const float*)d_in[0];   // [67440, 1024] fp32
    const float* W     = (const float*)d_in[1];   // [1024, 4096] fp32
    float* out         = (float*)d_out;           // [16860, 1024] fp32

    const size_t need = (size_t)NOUT * KDIM * sizeof(unsigned short); // 8 MB
    if (ws_size >= need) {
        unsigned short* Wb = (unsigned short*)d_ws;   // [1024, 4096] bf16
        cast_w<<<dim3((NOUT * KDIM / 4) / 256), 256, 0, stream>>>(W, Wb);
        gemm_fused<<<dim3(NOUT / BN, MPAD / BM), 256, 0, stream>>>(feats, Wb, out);
    } else {
        naive_fb<<<dim3(MTOK, 4), 256, 0, stream>>>(feats, W, out);
    }
}

// Round 4
// 701.923 us; speedup vs baseline: 1.8607x; 1.8607x over previous
//
#include <hip/hip_runtime.h>
#include <hip/hip_bf16.h>

// ---- static problem geometry (from reference: IMAGE_SIZES // 14) ----
// hp x wp per image: (110,110)(80,110)(110,64)(56,90)(108,108)(110,80)(64,64)(90,110)
// token counts: 12100 8800 7040 5040 11664 8800 4096 9900  -> 67440
// merged (n/4): 3025 2200 1760 1260 2916 2200 1024 2475    -> 16860
#define MTOK  16860
#define MPAD  16896   // 132 * 128
#define NOUT  1024
#define KDIM  4096

__device__ __constant__ int c_mend[8] = {3025,5225,6985,8245,11161,13361,14385,16860};
__device__ __constant__ int c_moff[8] = {0,3025,5225,6985,8245,11161,13361,14385};
__device__ __constant__ int c_foff[8] = {0,12100,20900,27940,32980,44644,53444,57540};
__device__ __constant__ int c_wp[8]   = {110,110,64,90,108,80,64,110};

typedef __attribute__((ext_vector_type(8))) short          bf16x8;  // 8 bf16 = 4 VGPRs
typedef __attribute__((ext_vector_type(8))) unsigned short u16x8;
typedef __attribute__((ext_vector_type(4))) float          f32x4;

__device__ __forceinline__ unsigned short f2bf(float f) {
    unsigned int u = __float_as_uint(f);
    u += 0x7FFFu + ((u >> 16) & 1u);   // round-to-nearest-even
    return (unsigned short)(u >> 16);
}

__device__ __forceinline__ void async_copy16(const void* g, void* l) {
    __builtin_amdgcn_global_load_lds(
        (const __attribute__((address_space(1))) void*)g,
        (__attribute__((address_space(3))) void*)l, 16, 0, 0);
}

// ---- kernel 1: 2x2 patch merge + fp32->bf16 cast (pad rows zeroed) ----
// merged[t][d*4 + ki*2 + kj] = feats[foff + (2i+ki)*wp + (2j+kj)][d]
__global__ __launch_bounds__(256) void merge_cast(const float* __restrict__ feats,
                                                  unsigned short* __restrict__ merged) {
    const int d = threadIdx.x * 4;
#pragma unroll
    for (int it = 0; it < 4; ++it) {
        int t = blockIdx.x * 4 + it;
        unsigned short* o = merged + (size_t)t * 4096 + d * 4;
        if (t >= MTOK) {   // zero pad rows 16860..16895
            *(u16x8*)(o)     = (u16x8)0;
            *(u16x8*)(o + 8) = (u16x8)0;
            continue;
        }
        int im = 0;
        while (t >= c_mend[im]) im++;
        int r   = t - c_moff[im];
        int wp  = c_wp[im];
        int wp2 = wp >> 1;
        int i = r / wp2, j = r - i * wp2;
        const float* p00 = feats + (size_t)(c_foff[im] + (2*i)*wp + 2*j) * 1024;
        const float* p01 = p00 + 1024;
        const float* p10 = p00 + (size_t)wp * 1024;
        const float* p11 = p10 + 1024;
        float4 a = *(const float4*)(p00 + d);
        float4 b = *(const float4*)(p01 + d);
        float4 c = *(const float4*)(p10 + d);
        float4 e = *(const float4*)(p11 + d);
        u16x8 lo, hi;
        lo[0]=f2bf(a.x); lo[1]=f2bf(b.x); lo[2]=f2bf(c.x); lo[3]=f2bf(e.x);
        lo[4]=f2bf(a.y); lo[5]=f2bf(b.y); lo[6]=f2bf(c.y); lo[7]=f2bf(e.y);
        hi[0]=f2bf(a.z); hi[1]=f2bf(b.z); hi[2]=f2bf(c.z); hi[3]=f2bf(e.z);
        hi[4]=f2bf(a.w); hi[5]=f2bf(b.w); hi[6]=f2bf(c.w); hi[7]=f2bf(e.w);
        *(u16x8*)(o)     = lo;
        *(u16x8*)(o + 8) = hi;
    }
}

// ---- kernel 2: weight fp32 -> bf16 (already [N][K] row-major = B^T) ----
__global__ __launch_bounds__(256) void cast_w(const float* __restrict__ W,
                                              unsigned short* __restrict__ Wb) {
    size_t g = (size_t)(blockIdx.x * 256 + threadIdx.x) * 4;
    float4 v = *(const float4*)(W + g);
    *(ushort4*)(Wb + g) = make_ushort4(f2bf(v.x), f2bf(v.y), f2bf(v.z), f2bf(v.w));
}

// ---- kernel 3: C[M,N] = A[M,K] * B[N,K]^T, bf16 in, fp32 out ----
// Single-barrier software pipeline: stage(k+1) is issued AFTER the barrier
// that consumes stage(k), so every global_load_lds is in flight for one full
// iteration before the vmcnt(0) drain at the next __syncthreads. LDS dbuf.
// Race-safety: reads of buf b at iter k complete before barrier k+1 (compiler
// emits lgkmcnt(0) before s_barrier); writes to buf b for iter k+2 are issued
// only after barrier k+1.
#define BM 128
#define BN 128
#define BK 32
__global__ __launch_bounds__(256) void gemm_bt(const unsigned short* __restrict__ A,
                                               const unsigned short* __restrict__ B,
                                               float* __restrict__ C) {
    __shared__ unsigned short lA[2][BM * BK];   // 2 x 8 KiB
    __shared__ unsigned short lB[2][BN * BK];   // 2 x 8 KiB

    const int bn = blockIdx.x, bm = blockIdx.y;   // bn fastest: A-tile L3 sharing
    const int tid  = threadIdx.x;
    const int wave = tid >> 6, lane = tid & 63;
    const int wm = (wave >> 1) * 64, wn = (wave & 1) * 64;

    const int lrow = lane >> 2;          // 0..15
    const int lcol = (lane & 3) * 8;     // 0,8,16,24 (bf16 elems)

    const unsigned short* Abase = A + (size_t)bm * BM * KDIM;
    const unsigned short* Bbase = B + (size_t)bn * BN * KDIM;

    f32x4 acc[4][4];
#pragma unroll
    for (int a = 0; a < 4; ++a)
#pragma unroll
        for (int b = 0; b < 4; ++b) acc[a][b] = (f32x4){0.f, 0.f, 0.f, 0.f};

    const int mrow = lane & 15;
    const int kq   = (lane >> 4) * 8;    // 0,8,16,24

    // prologue: stage k0=0 into buffer 0
#pragma unroll
    for (int r = 0; r < 2; ++r) {
        int chunk = wave * 2 + r;            // 0..7 (1 KiB LDS chunks)
        int row   = chunk * 16 + lrow;       // 0..127
        async_copy16(Abase + (size_t)row * KDIM + lcol, &lA[0][chunk * 512 + lane * 8]);
        async_copy16(Bbase + (size_t)row * KDIM + lcol, &lB[0][chunk * 512 + lane * 8]);
    }

    for (int k0 = 0; k0 < KDIM; k0 += BK) {
        const int cur = (k0 >> 5) & 1;
        __syncthreads();   // drains stage(k0) async writes; prior frag reads done

        if (k0 + BK < KDIM) {   // stage next tile into the other buffer
            const int nxt = cur ^ 1;
#pragma unroll
            for (int r = 0; r < 2; ++r) {
                int chunk = wave * 2 + r;
                int row   = chunk * 16 + lrow;
                async_copy16(Abase + (size_t)row * KDIM + (k0 + BK) + lcol,
                             &lA[nxt][chunk * 512 + lane * 8]);
                async_copy16(Bbase + (size_t)row * KDIM + (k0 + BK) + lcol,
                             &lB[nxt][chunk * 512 + lane * 8]);
            }
        }

        bf16x8 af[4], bfr[4];
#pragma unroll
        for (int a = 0; a < 4; ++a) {
            af[a]  = *(const bf16x8*)&lA[cur][(wm + a * 16 + mrow) * BK + kq];
            bfr[a] = *(const bf16x8*)&lB[cur][(wn + a * 16 + mrow) * BK + kq];
        }
#pragma unroll
        for (int a = 0; a < 4; ++a)
#pragma unroll
            for (int b = 0; b < 4; ++b)
                acc[a][b] = __builtin_amdgcn_mfma_f32_16x16x32_bf16(af[a], bfr[b], acc[a][b], 0, 0, 0);
        // no second barrier: next iter's barrier orders buffer reuse
    }

    // epilogue: C/D layout col=lane&15, row=(lane>>4)*4+reg
    const int col   = lane & 15;
    const int rquad = (lane >> 4) * 4;
#pragma unroll
    for (int a = 0; a < 4; ++a) {
        int gm0 = bm * BM + wm + a * 16 + rquad;
#pragma unroll
        for (int b = 0; b < 4; ++b) {
            int gn = bn * BN + wn + b * 16 + col;
#pragma unroll
            for (int rg = 0; rg < 4; ++rg) {
                int gm = gm0 + rg;
                if (gm < MTOK) C[(size_t)gm * NOUT + gn] = acc[a][b][rg];
            }
        }
    }
}

// ---- fallback (ws too small): exact fp32, slow but correct ----
__global__ __launch_bounds__(256) void naive_fb(const float* __restrict__ feats,
                                                const float* __restrict__ W,
                                                float* __restrict__ out) {
    int t = blockIdx.x;
    int o = blockIdx.y * 256 + threadIdx.x;
    int im = 0;
    while (t >= c_mend[im]) im++;
    int r = t - c_moff[im];
    int wp = c_wp[im], wp2 = wp >> 1;
    int i = r / wp2, j = r - i * wp2;
    const float* f00 = feats + (size_t)(c_foff[im] + (2*i)*wp + 2*j) * 1024;
    const float* f10 = f00 + (size_t)wp * 1024;
    const float* w = W + (size_t)o * 4096;
    float s = 0.f;
    for (int d = 0; d < 1024; ++d)
        s += f00[d] * w[d*4] + f00[d+1024] * w[d*4+1] + f10[d] * w[d*4+2] + f10[d+1024] * w[d*4+3];
    out[(size_t)t * 1024 + o] = s;
}

extern "C" void kernel_launch(void* const* d_in, const int* in_sizes, int n_in,
                              void* d_out, int out_size, void* d_ws, size_t ws_size,
                              hipStream_t stream) {
    const float* feats = (const float*)d_in[0];   // [67440, 1024] fp32
    const float* W     = (const float*)d_in[1];   // [1024, 4096] fp32
    float* out         = (float*)d_out;           // [16860, 1024] fp32

    const size_t need = ((size_t)MPAD + 1024) * KDIM * sizeof(unsigned short); // ~147 MB
    if (ws_size >= need) {
        unsigned short* merged = (unsigned short*)d_ws;          // [MPAD, 4096] bf16
        unsigned short* Wb     = merged + (size_t)MPAD * KDIM;   // [1024, 4096] bf16
        merge_cast<<<dim3(MPAD / 4), 256, 0, stream>>>(feats, merged);
        cast_w<<<dim3((NOUT * KDIM / 4) / 256), 256, 0, stream>>>(W, Wb);
        gemm_bt<<<dim3(NOUT / BN, MPAD / BM), 256, 0, stream>>>(merged, Wb, out);
    } else {
        naive_fb<<<dim3(MTOK, 4), 256, 0, stream>>>(feats, W, out);
    }
}